// Round 7
// baseline (499.532 us; speedup 1.0000x reference)
//
#include <hip/hip_runtime.h>
#include <hip/hip_bf16.h>
#include <stdint.h>

#define M_TIME 64
#define N_DICT 20000
#define B_VOX  8192

#define NTILES 313    // ceil(20000/64); last tile padded with zeros

typedef short v8s __attribute__((ext_vector_type(8)));   // 8 bf16 (bit pattern)
typedef float v4f __attribute__((ext_vector_type(4)));

__device__ __forceinline__ unsigned short bf16h(float x) {   // RNE fp32->bf16
    unsigned int u = __float_as_uint(x);
    return (unsigned short)((u + 0x7fffu + ((u >> 16) & 1u)) >> 16);
}
__device__ __forceinline__ float bf16f(unsigned short h) {
    return __uint_as_float(((unsigned int)h) << 16);
}
__device__ __forceinline__ unsigned long long u64max(unsigned long long a, unsigned long long b) { return a > b ? a : b; }
__device__ __forceinline__ unsigned umin32(unsigned a, unsigned b) { return a < b ? a : b; }
__device__ __forceinline__ unsigned umax32(unsigned a, unsigned b) { return a > b ? a : b; }

// ---------------------------------------------------------------------------
// Prepass: split y into bf16 hi/lo ONCE, packed in the exact LDS tile layout:
// yp[((T*4 + t)*16 + kq)*64 + n_l], t = {yr_hi, yr_lo, yi_hi, yi_lo}.
// ---------------------------------------------------------------------------
__global__ __launch_bounds__(256) void split_y(
    const float* __restrict__ yr, const float* __restrict__ yi,
    ushort4* __restrict__ yp)
{
    const int u = blockIdx.x * 256 + threadIdx.x;   // [arr][T][kq][n_l]
    const int n_l = u & 63;
    const int kq  = (u >> 6) & 15;
    const int T   = (u >> 10) % NTILES;
    const int arr = u / (NTILES * 1024);
    if (arr > 1) return;
    const float* P = arr ? yi : yr;
    const int n_g = T * 64 + n_l;
    float v0 = 0.f, v1 = 0.f, v2 = 0.f, v3 = 0.f;
    if (n_g < N_DICT) {
        v0 = P[(kq * 4 + 0) * N_DICT + n_g];
        v1 = P[(kq * 4 + 1) * N_DICT + n_g];
        v2 = P[(kq * 4 + 2) * N_DICT + n_g];
        v3 = P[(kq * 4 + 3) * N_DICT + n_g];
    }
    ushort4 H, L;
    H.x = bf16h(v0); L.x = bf16h(v0 - bf16f(H.x));
    H.y = bf16h(v1); L.y = bf16h(v1 - bf16f(H.y));
    H.z = bf16h(v2); L.z = bf16h(v2 - bf16f(H.z));
    H.w = bf16h(v3); L.w = bf16h(v3 - bf16f(H.w));
    yp[(((size_t)T * 4 + arr * 2 + 0) * 16 + kq) * 64 + n_l] = H;
    yp[(((size_t)T * 4 + arr * 2 + 1) * 16 + kq) * 64 + n_l] = L;
}

// ---------------------------------------------------------------------------
// Phase A: bf16-split MFMA GEMM + per-chunk top-2 (u32 packed comparator).
// Packed key: (sim_bits & 0xFFFFE000) | (0x1FFF - n_local). fp32 bits are
// monotone for sim>=0; 13-bit truncation (0.1%) is inside the 2% rescue
// margin; inverted n_local -> ties pick the smaller index.
// Staging is register-prefetched (pf loaded during previous tile's MFMA).
// ---------------------------------------------------------------------------
__global__ __launch_bounds__(256, 2) void gemm_pre(
    const float* __restrict__ ir, const float* __restrict__ ii,
    const ushort4* __restrict__ yp,
    unsigned* __restrict__ cand, int tpc, int slots)
{
    __shared__ float4 ys4[2048];            // 32 KB tile
    __shared__ unsigned xm[2][2][16][2];    // [wb][bt][col][a1,a2]
    ushort4* ysu = (ushort4*)ys4;

    const int tid  = threadIdx.x;
    const int wave = tid >> 6, lane = tid & 63;
    const int quad = lane >> 4, col = lane & 15;
    const int wb   = wave >> 1, wn = wave & 1;
    const int vox_w = blockIdx.x * 64 + wb * 32;
    const int chunk = blockIdx.y;
    const int T0 = chunk * tpc;
    const int T1 = (T0 + tpc < NTILES) ? T0 + tpc : NTILES;

    // ---- issue prefetch of tile T0 first (overlaps fragment build) ----
    float4 pf[8];
    {
        const float4* src = (const float4*)(yp + (size_t)T0 * 4096);
#pragma unroll
        for (int p = 0; p < 8; ++p) pf[p] = src[tid + p * 256];
    }

    // ---- persistent input B-frags: [arr][bt][h] hi/lo (once per block) ----
    v8s fh[2][2][2], fl[2][2][2];
#pragma unroll
    for (int arr = 0; arr < 2; ++arr) {
        const float* P = arr ? ii : ir;
#pragma unroll
        for (int bt = 0; bt < 2; ++bt) {
            const int b = vox_w + bt * 16 + col;
#pragma unroll
            for (int h = 0; h < 2; ++h) {
                v8s H, L;
#pragma unroll
                for (int j = 0; j < 8; ++j) {
                    const int k = h * 32 + quad * 8 + j;
                    float x = P[k * B_VOX + b];
                    unsigned short hb = bf16h(x);
                    H[j] = (short)hb;
                    L[j] = (short)bf16h(x - bf16f(hb));
                }
                fh[arr][bt][h] = H; fl[arr][bt][h] = L;
            }
        }
    }

    unsigned t2a[2] = {0u, 0u}, t2b[2] = {0u, 0u};

    for (int T = T0; T < T1; ++T) {
        __syncthreads();                        // previous tile consumed
#pragma unroll
        for (int p = 0; p < 8; ++p) ys4[tid + p * 256] = pf[p];
        __syncthreads();
        if (T + 1 < T1) {                       // prefetch next tile
            const float4* src = (const float4*)(yp + (size_t)(T + 1) * 4096);
#pragma unroll
            for (int p = 0; p < 8; ++p) pf[p] = src[tid + p * 256];
        }

        v4f acc[2][2][4];                       // [bt][nt][rr,ri,s1,s2]
#pragma unroll
        for (int bt = 0; bt < 2; ++bt)
#pragma unroll
            for (int nt = 0; nt < 2; ++nt)
#pragma unroll
                for (int d = 0; d < 4; ++d) acc[bt][nt][d] = (v4f){0.f, 0.f, 0.f, 0.f};

#pragma unroll
        for (int h = 0; h < 2; ++h) {
            const int kq0 = h * 8 + quad * 2;
#pragma unroll
            for (int nt = 0; nt < 2; ++nt) {
                const int nrow = (wn * 2 + nt) * 16 + col;
                v8s yf[4];                      // yrh, yrl, yih, yil
#pragma unroll
                for (int t = 0; t < 4; ++t) {
                    ushort4 lo = ysu[(t * 16 + kq0    ) * 64 + nrow];
                    ushort4 hi = ysu[(t * 16 + kq0 + 1) * 64 + nrow];
                    v8s f;
                    f[0] = (short)lo.x; f[1] = (short)lo.y; f[2] = (short)lo.z; f[3] = (short)lo.w;
                    f[4] = (short)hi.x; f[5] = (short)hi.y; f[6] = (short)hi.z; f[7] = (short)hi.w;
                    yf[t] = f;
                }
#pragma unroll
                for (int bt = 0; bt < 2; ++bt) {
#define MF(A, B, C) C = __builtin_amdgcn_mfma_f32_16x16x32_bf16(A, B, C, 0, 0, 0)
                    MF(yf[0], fh[0][bt][h], acc[bt][nt][0]);   // rr: yrh*irh
                    MF(yf[0], fl[0][bt][h], acc[bt][nt][0]);   //     yrh*irl
                    MF(yf[1], fh[0][bt][h], acc[bt][nt][0]);   //     yrl*irh
                    MF(yf[2], fh[0][bt][h], acc[bt][nt][1]);   // ri
                    MF(yf[2], fl[0][bt][h], acc[bt][nt][1]);
                    MF(yf[3], fh[0][bt][h], acc[bt][nt][1]);
                    MF(yf[0], fh[1][bt][h], acc[bt][nt][2]);   // s1
                    MF(yf[0], fl[1][bt][h], acc[bt][nt][2]);
                    MF(yf[1], fh[1][bt][h], acc[bt][nt][2]);
                    MF(yf[2], fh[1][bt][h], acc[bt][nt][3]);   // s2
                    MF(yf[2], fl[1][bt][h], acc[bt][nt][3]);
                    MF(yf[3], fh[1][bt][h], acc[bt][nt][3]);
#undef MF
                }
            }
        }

        // ---- sim + top-2, u32 min/max network ----
        const int tl = T - T0;
#pragma unroll
        for (int nt = 0; nt < 2; ++nt) {
            const int inv_base = 0x1FFF - (tl * 64 + (wn * 2 + nt) * 16 + quad * 4);
#pragma unroll
            for (int bt = 0; bt < 2; ++bt) {
                v4f RR = acc[bt][nt][0], RI = acc[bt][nt][1];
                v4f S1 = acc[bt][nt][2], S2 = acc[bt][nt][3];
#pragma unroll
                for (int r = 0; r < 4; ++r) {
                    float s = fmaf(RR[r], RR[r], fmaf(RI[r], RI[r],
                              fmaf(S1[r], S1[r], S2[r] * S2[r])));
                    unsigned pb = (__float_as_uint(s) & 0xFFFFE000u)
                                | (unsigned)(inv_base - r);
                    unsigned lo = umin32(pb, t2a[bt]);
                    t2a[bt] = umax32(pb, t2a[bt]);
                    t2b[bt] = umax32(t2b[bt], lo);
                }
            }
        }
    }

    // ---- cross-lane top-2 merge over quads (lanes c, c+16, c+32, c+48) ----
    unsigned fa1[2], fa2[2];
#pragma unroll
    for (int bt = 0; bt < 2; ++bt) {
        unsigned a1 = t2a[bt], a2 = t2b[bt];
#pragma unroll
        for (int d = 16; d <= 32; d <<= 1) {
            unsigned b1 = (unsigned)__shfl_xor((int)a1, d, 64);
            unsigned b2 = (unsigned)__shfl_xor((int)a2, d, 64);
            unsigned mn = umin32(a1, b1);
            a1 = umax32(a1, b1);
            a2 = umax32(mn, umax32(a2, b2));
        }
        fa1[bt] = a1; fa2[bt] = a2;
    }
    // ---- cross-wave (wn) merge: wn==1 publishes, wn==0 writes ----
    __syncthreads();
    if (wn == 1 && lane < 16) {
#pragma unroll
        for (int bt = 0; bt < 2; ++bt) { xm[wb][bt][lane][0] = fa1[bt]; xm[wb][bt][lane][1] = fa2[bt]; }
    }
    __syncthreads();
    if (wn == 0 && lane < 16) {
#pragma unroll
        for (int bt = 0; bt < 2; ++bt) {
            unsigned b1 = xm[wb][bt][lane][0];
            unsigned b2 = xm[wb][bt][lane][1];
            unsigned m1 = umax32(fa1[bt], b1);
            unsigned m2 = umax32(umin32(fa1[bt], b1), umax32(fa2[bt], b2));
            const size_t vox = vox_w + bt * 16 + lane;
            cand[vox * slots + chunk * 2 + 0] = m1;
            cand[vox * slots + chunk * 2 + 1] = m2;
        }
    }
}

// ---------------------------------------------------------------------------
// Phase B (fused): exact fp32 rescore of candidates within 2% of approx max,
// winner lane computes scales and writes the 4 output rows directly.
// One wave per voxel.
// ---------------------------------------------------------------------------
__global__ __launch_bounds__(256) void rescore_finish(
    const float* __restrict__ ir, const float* __restrict__ ii,
    const float* __restrict__ yr, const float* __restrict__ yi,
    const float* __restrict__ inv, const float* __restrict__ x1,
    const float* __restrict__ x2,
    const unsigned* __restrict__ cand, int slots, int tpc,
    float* __restrict__ out)
{
    const int tid  = threadIdx.x;
    const int vox  = blockIdx.x * 4 + (tid >> 6);
    const int slot = tid & 63;

    unsigned p = (slot < slots) ? cand[(size_t)vox * slots + slot] : 0u;
    float sa = __uint_as_float(p & 0xFFFFE000u);
    const int chunkc = slot >> 1;
    const int nn = chunkc * tpc * 64 + (0x1FFF - (int)(p & 0x1FFFu));

    float amax = sa;
#pragma unroll
    for (int d = 1; d <= 32; d <<= 1) amax = fmaxf(amax, __shfl_xor(amax, d, 64));

    unsigned long long q = 0ull;
    float rr = 0.f, ri = 0.f, s1 = 0.f, s2 = 0.f;
    const bool active = (slot < slots) && (nn >= 0) && (nn < N_DICT)
                     && (sa >= 0.98f * amax);
    if (active) {
        for (int m = 0; m < M_TIME; ++m) {
            float a  = yr[(size_t)m * N_DICT + nn];
            float c  = yi[(size_t)m * N_DICT + nn];
            float vr = ir[m * B_VOX + vox];
            float vi = ii[m * B_VOX + vox];
            rr = fmaf(vr, a, rr); ri = fmaf(vr, c, ri);
            s1 = fmaf(vi, a, s1); s2 = fmaf(vi, c, s2);
        }
        float s = fmaf(rr, rr, fmaf(ri, ri, fmaf(s1, s1, s2 * s2)));
        q = (((unsigned long long)__float_as_uint(s)) << 32)
          | (unsigned long long)(0xFFFFFFFFu - (unsigned)nn);  // ties -> smaller n
    }
    unsigned long long qm = q;
#pragma unroll
    for (int d = 1; d <= 32; d <<= 1) qm = u64max(qm, __shfl_xor(qm, d, 64));

    if (active && q == qm && qm != 0ull) {       // exactly one lane (n in key)
        float ss = inv[nn];
        out[0 * B_VOX + vox] = (rr + s2) * ss;   // sum(yr*ir + yi*ii) * inv
        out[1 * B_VOX + vox] = (s1 - ri) * ss;   // sum(yr*ii - yi*ir) * inv
        out[2 * B_VOX + vox] = x1[nn];
        out[3 * B_VOX + vox] = x2[nn];
    }
}

// ---------------------------------------------------------------------------
// Last-resort fallbacks (tiny ws): fp32 brute-force argmax + finish.
// ---------------------------------------------------------------------------
__global__ __launch_bounds__(256, 3) void argmax_naive(
    const float* __restrict__ ir, const float* __restrict__ ii,
    const float* __restrict__ yr, const float* __restrict__ yi,
    int* __restrict__ idxout)
{
    int b = blockIdx.x * 256 + threadIdx.x;
    float bs = -1.0f; int bn = 0;
    for (int n = 0; n < N_DICT; ++n) {
        float a_rr = 0.f, a_ri = 0.f, a_s1 = 0.f, a_s2 = 0.f;
        for (int m = 0; m < M_TIME; ++m) {
            float a = yr[m * N_DICT + n], c = yi[m * N_DICT + n];
            float vr = ir[m * B_VOX + b], vi = ii[m * B_VOX + b];
            a_rr = fmaf(vr, a, a_rr); a_ri = fmaf(vr, c, a_ri);
            a_s1 = fmaf(vi, a, a_s1); a_s2 = fmaf(vi, c, a_s2);
        }
        float sim = fmaf(a_rr, a_rr, fmaf(a_ri, a_ri, fmaf(a_s1, a_s1, a_s2 * a_s2)));
        if (sim > bs) { bs = sim; bn = n; }
    }
    idxout[b] = bn;
}

__global__ void finish_k(const float* __restrict__ ir, const float* __restrict__ ii,
                         const float* __restrict__ yr, const float* __restrict__ yi,
                         const float* __restrict__ inv, const float* __restrict__ x1,
                         const float* __restrict__ x2,
                         const int* __restrict__ idxin, float* __restrict__ out)
{
    int b = blockIdx.x * blockDim.x + threadIdx.x;
    int idx = idxin[b];
    float ar = 0.f, ai = 0.f;
    for (int m = 0; m < M_TIME; ++m) {
        float a  = yr[(size_t)m * N_DICT + idx];
        float c  = yi[(size_t)m * N_DICT + idx];
        float vr = ir[m * B_VOX + b];
        float vi = ii[m * B_VOX + b];
        ar = fmaf(a, vr, ar); ar = fmaf(c, vi, ar);
        ai = fmaf(a, vi, ai); ai = fmaf(-c, vr, ai);
    }
    float s = inv[idx];
    out[0 * B_VOX + b] = ar * s;
    out[1 * B_VOX + b] = ai * s;
    out[2 * B_VOX + b] = x1[idx];
    out[3 * B_VOX + b] = x2[idx];
}

extern "C" void kernel_launch(void* const* d_in, const int* in_sizes, int n_in,
                              void* d_out, int out_size, void* d_ws, size_t ws_size,
                              hipStream_t stream) {
    const float* ir  = (const float*)d_in[0];
    const float* ii  = (const float*)d_in[1];
    const float* yr  = (const float*)d_in[2];
    const float* yi  = (const float*)d_in[3];
    const float* inv = (const float*)d_in[4];
    const float* x1  = (const float*)d_in[5];
    const float* x2  = (const float*)d_in[6];
    float* out = (float*)d_out;

    const size_t yp_bytes = (size_t)NTILES * 4096 * sizeof(ushort4);   // 10.26 MB

    // pick largest chunk count whose cand buffer fits alongside yp
    int CH = 0;
    for (int c = 16; c >= 4; c >>= 1) {
        size_t cand_bytes = (size_t)B_VOX * (2 * c) * sizeof(unsigned);
        if (ws_size >= cand_bytes + yp_bytes) { CH = c; break; }
    }

    if (CH > 0) {
        const int slots = 2 * CH;
        const int tpc   = (NTILES + CH - 1) / CH;
        unsigned* cand = (unsigned*)d_ws;
        ushort4* yp = (ushort4*)((char*)d_ws + (size_t)B_VOX * slots * sizeof(unsigned));

        const int units = 2 * NTILES * 1024;
        split_y<<<(units + 255) / 256, 256, 0, stream>>>(yr, yi, yp);
        gemm_pre<<<dim3(B_VOX / 64, CH), 256, 0, stream>>>(ir, ii, yp, cand, tpc, slots);
        rescore_finish<<<B_VOX / 4, 256, 0, stream>>>(ir, ii, yr, yi, inv, x1, x2,
                                                      cand, slots, tpc, out);
    } else {
        int* idxo = (int*)(out + 3 * B_VOX);   // alias out row 3 (read-before-write)
        argmax_naive<<<B_VOX / 256, 256, 0, stream>>>(ir, ii, yr, yi, idxo);
        finish_k<<<B_VOX / 256, 256, 0, stream>>>(ir, ii, yr, yi,
                                                  inv, x1, x2, idxo, out);
    }
}

// Round 8
// 305.593 us; speedup vs baseline: 1.6346x; 1.6346x over previous
//
#include <hip/hip_runtime.h>
#include <hip/hip_bf16.h>
#include <stdint.h>

#define M_TIME 64
#define N_DICT 20000
#define B_VOX  8192

#define NTILES 313    // ceil(20000/64); last tile padded with zeros

typedef short v8s __attribute__((ext_vector_type(8)));   // 8 bf16 (bit pattern)
typedef float v4f __attribute__((ext_vector_type(4)));
typedef __attribute__((address_space(3))) unsigned int  lds_u32;
typedef const __attribute__((address_space(1))) unsigned int glb_u32;

__device__ __forceinline__ unsigned short bf16h(float x) {   // RNE fp32->bf16
    unsigned int u = __float_as_uint(x);
    return (unsigned short)((u + 0x7fffu + ((u >> 16) & 1u)) >> 16);
}
__device__ __forceinline__ float bf16f(unsigned short h) {
    return __uint_as_float(((unsigned int)h) << 16);
}
__device__ __forceinline__ unsigned long long u64max(unsigned long long a, unsigned long long b) { return a > b ? a : b; }
__device__ __forceinline__ unsigned umin32(unsigned a, unsigned b) { return a < b ? a : b; }
__device__ __forceinline__ unsigned umax32(unsigned a, unsigned b) { return a > b ? a : b; }

// ---------------------------------------------------------------------------
// Prepass: split y into bf16 hi/lo ONCE, packed in the exact LDS tile layout:
// yp[((T*4 + t)*16 + kq)*64 + n_l], t = {yr_hi, yr_lo, yi_hi, yi_lo}.
// ---------------------------------------------------------------------------
__global__ __launch_bounds__(256) void split_y(
    const float* __restrict__ yr, const float* __restrict__ yi,
    ushort4* __restrict__ yp)
{
    const int u = blockIdx.x * 256 + threadIdx.x;   // [arr][T][kq][n_l]
    const int n_l = u & 63;
    const int kq  = (u >> 6) & 15;
    const int T   = (u >> 10) % NTILES;
    const int arr = u / (NTILES * 1024);
    if (arr > 1) return;
    const float* P = arr ? yi : yr;
    const int n_g = T * 64 + n_l;
    float v0 = 0.f, v1 = 0.f, v2 = 0.f, v3 = 0.f;
    if (n_g < N_DICT) {
        v0 = P[(kq * 4 + 0) * N_DICT + n_g];
        v1 = P[(kq * 4 + 1) * N_DICT + n_g];
        v2 = P[(kq * 4 + 2) * N_DICT + n_g];
        v3 = P[(kq * 4 + 3) * N_DICT + n_g];
    }
    ushort4 H, L;
    H.x = bf16h(v0); L.x = bf16h(v0 - bf16f(H.x));
    H.y = bf16h(v1); L.y = bf16h(v1 - bf16f(H.y));
    H.z = bf16h(v2); L.z = bf16h(v2 - bf16f(H.z));
    H.w = bf16h(v3); L.w = bf16h(v3 - bf16f(H.w));
    yp[(((size_t)T * 4 + arr * 2 + 0) * 16 + kq) * 64 + n_l] = H;
    yp[(((size_t)T * 4 + arr * 2 + 1) * 16 + kq) * 64 + n_l] = L;
}

// ---------------------------------------------------------------------------
// Phase A: bf16-split MFMA GEMM + per-chunk top-2 (u32 packed comparator).
// Staging: __builtin_amdgcn_global_load_lds width=16 (direct global->LDS DMA,
// no VGPR round-trip -- round 7's register prefetch spilled to scratch and
// cost 560 MB of WRITE_SIZE per dispatch).
// Packed key: (sim_bits & 0xFFFFE000) | (0x1FFF - n_local); rescued exactly.
// ---------------------------------------------------------------------------
__global__ __launch_bounds__(256, 2) void gemm_pre(
    const float* __restrict__ ir, const float* __restrict__ ii,
    const ushort4* __restrict__ yp,
    unsigned* __restrict__ cand, int tpc, int slots)
{
    __shared__ float4 ys4[2048];            // 32 KB tile
    __shared__ unsigned xm[2][2][16][2];    // [wb][bt][col][a1,a2]
    ushort4* ysu = (ushort4*)ys4;

    const int tid  = threadIdx.x;
    const int wave = tid >> 6, lane = tid & 63;
    const int quad = lane >> 4, col = lane & 15;
    const int wb   = wave >> 1, wn = wave & 1;
    const int vox_w = blockIdx.x * 64 + wb * 32;
    const int chunk = blockIdx.y;
    const int T0 = chunk * tpc;
    const int T1 = (T0 + tpc < NTILES) ? T0 + tpc : NTILES;

    // ---- persistent input B-frags: [arr][bt][h] hi/lo (once per block) ----
    v8s fh[2][2][2], fl[2][2][2];
#pragma unroll
    for (int arr = 0; arr < 2; ++arr) {
        const float* P = arr ? ii : ir;
#pragma unroll
        for (int bt = 0; bt < 2; ++bt) {
            const int b = vox_w + bt * 16 + col;
#pragma unroll
            for (int h = 0; h < 2; ++h) {
                v8s H, L;
#pragma unroll
                for (int j = 0; j < 8; ++j) {
                    const int k = h * 32 + quad * 8 + j;
                    float x = P[k * B_VOX + b];
                    unsigned short hb = bf16h(x);
                    H[j] = (short)hb;
                    L[j] = (short)bf16h(x - bf16f(hb));
                }
                fh[arr][bt][h] = H; fl[arr][bt][h] = L;
            }
        }
    }

    unsigned t2a[2] = {0u, 0u}, t2b[2] = {0u, 0u};

    for (int T = T0; T < T1; ++T) {
        __syncthreads();                        // previous tile consumed
        {   // ---- stage 32 KB via global->LDS DMA: 8 x (64 lanes x 16 B)/wave ----
            const float4* src = (const float4*)(yp + (size_t)T * 4096);
#pragma unroll
            for (int p = 0; p < 8; ++p) {
                const int base = p * 256 + wave * 64;        // wave-uniform
                __builtin_amdgcn_global_load_lds(
                    (glb_u32*)(src + base + lane),
                    (lds_u32*)(ys4 + base), 16, 0, 0);
            }
        }
        __syncthreads();                        // drains vmcnt before compute

        v4f acc[2][2][4];                       // [bt][nt][rr,ri,s1,s2]
#pragma unroll
        for (int bt = 0; bt < 2; ++bt)
#pragma unroll
            for (int nt = 0; nt < 2; ++nt)
#pragma unroll
                for (int d = 0; d < 4; ++d) acc[bt][nt][d] = (v4f){0.f, 0.f, 0.f, 0.f};

#pragma unroll
        for (int h = 0; h < 2; ++h) {
            const int kq0 = h * 8 + quad * 2;
#pragma unroll
            for (int nt = 0; nt < 2; ++nt) {
                const int nrow = (wn * 2 + nt) * 16 + col;
                v8s yf[4];                      // yrh, yrl, yih, yil
#pragma unroll
                for (int t = 0; t < 4; ++t) {
                    ushort4 lo = ysu[(t * 16 + kq0    ) * 64 + nrow];
                    ushort4 hi = ysu[(t * 16 + kq0 + 1) * 64 + nrow];
                    v8s f;
                    f[0] = (short)lo.x; f[1] = (short)lo.y; f[2] = (short)lo.z; f[3] = (short)lo.w;
                    f[4] = (short)hi.x; f[5] = (short)hi.y; f[6] = (short)hi.z; f[7] = (short)hi.w;
                    yf[t] = f;
                }
#pragma unroll
                for (int bt = 0; bt < 2; ++bt) {
#define MF(A, B, C) C = __builtin_amdgcn_mfma_f32_16x16x32_bf16(A, B, C, 0, 0, 0)
                    MF(yf[0], fh[0][bt][h], acc[bt][nt][0]);   // rr: yrh*irh
                    MF(yf[0], fl[0][bt][h], acc[bt][nt][0]);   //     yrh*irl
                    MF(yf[1], fh[0][bt][h], acc[bt][nt][0]);   //     yrl*irh
                    MF(yf[2], fh[0][bt][h], acc[bt][nt][1]);   // ri
                    MF(yf[2], fl[0][bt][h], acc[bt][nt][1]);
                    MF(yf[3], fh[0][bt][h], acc[bt][nt][1]);
                    MF(yf[0], fh[1][bt][h], acc[bt][nt][2]);   // s1
                    MF(yf[0], fl[1][bt][h], acc[bt][nt][2]);
                    MF(yf[1], fh[1][bt][h], acc[bt][nt][2]);
                    MF(yf[2], fh[1][bt][h], acc[bt][nt][3]);   // s2
                    MF(yf[2], fl[1][bt][h], acc[bt][nt][3]);
                    MF(yf[3], fh[1][bt][h], acc[bt][nt][3]);
#undef MF
                }
            }
        }

        // ---- sim + top-2, u32 min/max network ----
        const int tl = T - T0;
#pragma unroll
        for (int nt = 0; nt < 2; ++nt) {
            const int inv_base = 0x1FFF - (tl * 64 + (wn * 2 + nt) * 16 + quad * 4);
#pragma unroll
            for (int bt = 0; bt < 2; ++bt) {
                v4f RR = acc[bt][nt][0], RI = acc[bt][nt][1];
                v4f S1 = acc[bt][nt][2], S2 = acc[bt][nt][3];
#pragma unroll
                for (int r = 0; r < 4; ++r) {
                    float s = fmaf(RR[r], RR[r], fmaf(RI[r], RI[r],
                              fmaf(S1[r], S1[r], S2[r] * S2[r])));
                    unsigned pb = (__float_as_uint(s) & 0xFFFFE000u)
                                | (unsigned)(inv_base - r);
                    unsigned lo = umin32(pb, t2a[bt]);
                    t2a[bt] = umax32(pb, t2a[bt]);
                    t2b[bt] = umax32(t2b[bt], lo);
                }
            }
        }
    }

    // ---- cross-lane top-2 merge over quads (lanes c, c+16, c+32, c+48) ----
    unsigned fa1[2], fa2[2];
#pragma unroll
    for (int bt = 0; bt < 2; ++bt) {
        unsigned a1 = t2a[bt], a2 = t2b[bt];
#pragma unroll
        for (int d = 16; d <= 32; d <<= 1) {
            unsigned b1 = (unsigned)__shfl_xor((int)a1, d, 64);
            unsigned b2 = (unsigned)__shfl_xor((int)a2, d, 64);
            unsigned mn = umin32(a1, b1);
            a1 = umax32(a1, b1);
            a2 = umax32(mn, umax32(a2, b2));
        }
        fa1[bt] = a1; fa2[bt] = a2;
    }
    // ---- cross-wave (wn) merge: wn==1 publishes, wn==0 writes ----
    __syncthreads();
    if (wn == 1 && lane < 16) {
#pragma unroll
        for (int bt = 0; bt < 2; ++bt) { xm[wb][bt][lane][0] = fa1[bt]; xm[wb][bt][lane][1] = fa2[bt]; }
    }
    __syncthreads();
    if (wn == 0 && lane < 16) {
#pragma unroll
        for (int bt = 0; bt < 2; ++bt) {
            unsigned b1 = xm[wb][bt][lane][0];
            unsigned b2 = xm[wb][bt][lane][1];
            unsigned m1 = umax32(fa1[bt], b1);
            unsigned m2 = umax32(umin32(fa1[bt], b1), umax32(fa2[bt], b2));
            const size_t vox = vox_w + bt * 16 + lane;
            cand[vox * slots + chunk * 2 + 0] = m1;
            cand[vox * slots + chunk * 2 + 1] = m2;
        }
    }
}

// ---------------------------------------------------------------------------
// Phase B (fused): exact fp32 rescore of candidates within 2% of approx max,
// winner lane computes scales and writes the 4 output rows directly.
// One wave per voxel.
// ---------------------------------------------------------------------------
__global__ __launch_bounds__(256) void rescore_finish(
    const float* __restrict__ ir, const float* __restrict__ ii,
    const float* __restrict__ yr, const float* __restrict__ yi,
    const float* __restrict__ inv, const float* __restrict__ x1,
    const float* __restrict__ x2,
    const unsigned* __restrict__ cand, int slots, int tpc,
    float* __restrict__ out)
{
    const int tid  = threadIdx.x;
    const int vox  = blockIdx.x * 4 + (tid >> 6);
    const int slot = tid & 63;

    unsigned p = (slot < slots) ? cand[(size_t)vox * slots + slot] : 0u;
    float sa = __uint_as_float(p & 0xFFFFE000u);
    const int chunkc = slot >> 1;
    const int nn = chunkc * tpc * 64 + (0x1FFF - (int)(p & 0x1FFFu));

    float amax = sa;
#pragma unroll
    for (int d = 1; d <= 32; d <<= 1) amax = fmaxf(amax, __shfl_xor(amax, d, 64));

    unsigned long long q = 0ull;
    float rr = 0.f, ri = 0.f, s1 = 0.f, s2 = 0.f;
    const bool active = (slot < slots) && (nn >= 0) && (nn < N_DICT)
                     && (sa >= 0.98f * amax);
    if (active) {
        for (int m = 0; m < M_TIME; ++m) {
            float a  = yr[(size_t)m * N_DICT + nn];
            float c  = yi[(size_t)m * N_DICT + nn];
            float vr = ir[m * B_VOX + vox];
            float vi = ii[m * B_VOX + vox];
            rr = fmaf(vr, a, rr); ri = fmaf(vr, c, ri);
            s1 = fmaf(vi, a, s1); s2 = fmaf(vi, c, s2);
        }
        float s = fmaf(rr, rr, fmaf(ri, ri, fmaf(s1, s1, s2 * s2)));
        q = (((unsigned long long)__float_as_uint(s)) << 32)
          | (unsigned long long)(0xFFFFFFFFu - (unsigned)nn);  // ties -> smaller n
    }
    unsigned long long qm = q;
#pragma unroll
    for (int d = 1; d <= 32; d <<= 1) qm = u64max(qm, __shfl_xor(qm, d, 64));

    if (active && q == qm && qm != 0ull) {       // exactly one lane (n in key)
        float ss = inv[nn];
        out[0 * B_VOX + vox] = (rr + s2) * ss;   // sum(yr*ir + yi*ii) * inv
        out[1 * B_VOX + vox] = (s1 - ri) * ss;   // sum(yr*ii - yi*ir) * inv
        out[2 * B_VOX + vox] = x1[nn];
        out[3 * B_VOX + vox] = x2[nn];
    }
}

// ---------------------------------------------------------------------------
// Last-resort fallbacks (tiny ws): fp32 brute-force argmax + finish.
// ---------------------------------------------------------------------------
__global__ __launch_bounds__(256, 3) void argmax_naive(
    const float* __restrict__ ir, const float* __restrict__ ii,
    const float* __restrict__ yr, const float* __restrict__ yi,
    int* __restrict__ idxout)
{
    int b = blockIdx.x * 256 + threadIdx.x;
    float bs = -1.0f; int bn = 0;
    for (int n = 0; n < N_DICT; ++n) {
        float a_rr = 0.f, a_ri = 0.f, a_s1 = 0.f, a_s2 = 0.f;
        for (int m = 0; m < M_TIME; ++m) {
            float a = yr[m * N_DICT + n], c = yi[m * N_DICT + n];
            float vr = ir[m * B_VOX + b], vi = ii[m * B_VOX + b];
            a_rr = fmaf(vr, a, a_rr); a_ri = fmaf(vr, c, a_ri);
            a_s1 = fmaf(vi, a, a_s1); a_s2 = fmaf(vi, c, a_s2);
        }
        float sim = fmaf(a_rr, a_rr, fmaf(a_ri, a_ri, fmaf(a_s1, a_s1, a_s2 * a_s2)));
        if (sim > bs) { bs = sim; bn = n; }
    }
    idxout[b] = bn;
}

__global__ void finish_k(const float* __restrict__ ir, const float* __restrict__ ii,
                         const float* __restrict__ yr, const float* __restrict__ yi,
                         const float* __restrict__ inv, const float* __restrict__ x1,
                         const float* __restrict__ x2,
                         const int* __restrict__ idxin, float* __restrict__ out)
{
    int b = blockIdx.x * blockDim.x + threadIdx.x;
    int idx = idxin[b];
    float ar = 0.f, ai = 0.f;
    for (int m = 0; m < M_TIME; ++m) {
        float a  = yr[(size_t)m * N_DICT + idx];
        float c  = yi[(size_t)m * N_DICT + idx];
        float vr = ir[m * B_VOX + b];
        float vi = ii[m * B_VOX + b];
        ar = fmaf(a, vr, ar); ar = fmaf(c, vi, ar);
        ai = fmaf(a, vi, ai); ai = fmaf(-c, vr, ai);
    }
    float s = inv[idx];
    out[0 * B_VOX + b] = ar * s;
    out[1 * B_VOX + b] = ai * s;
    out[2 * B_VOX + b] = x1[idx];
    out[3 * B_VOX + b] = x2[idx];
}

extern "C" void kernel_launch(void* const* d_in, const int* in_sizes, int n_in,
                              void* d_out, int out_size, void* d_ws, size_t ws_size,
                              hipStream_t stream) {
    const float* ir  = (const float*)d_in[0];
    const float* ii  = (const float*)d_in[1];
    const float* yr  = (const float*)d_in[2];
    const float* yi  = (const float*)d_in[3];
    const float* inv = (const float*)d_in[4];
    const float* x1  = (const float*)d_in[5];
    const float* x2  = (const float*)d_in[6];
    float* out = (float*)d_out;

    const size_t yp_bytes = (size_t)NTILES * 4096 * sizeof(ushort4);   // 10.26 MB

    // pick largest chunk count whose cand buffer fits alongside yp
    int CH = 0;
    for (int c = 16; c >= 4; c >>= 1) {
        size_t cand_bytes = (size_t)B_VOX * (2 * c) * sizeof(unsigned);
        if (ws_size >= cand_bytes + yp_bytes) { CH = c; break; }
    }

    if (CH > 0) {
        const int slots = 2 * CH;
        const int tpc   = (NTILES + CH - 1) / CH;
        unsigned* cand = (unsigned*)d_ws;
        ushort4* yp = (ushort4*)((char*)d_ws + (size_t)B_VOX * slots * sizeof(unsigned));

        const int units = 2 * NTILES * 1024;
        split_y<<<(units + 255) / 256, 256, 0, stream>>>(yr, yi, yp);
        gemm_pre<<<dim3(B_VOX / 64, CH), 256, 0, stream>>>(ir, ii, yp, cand, tpc, slots);
        rescore_finish<<<B_VOX / 4, 256, 0, stream>>>(ir, ii, yr, yi, inv, x1, x2,
                                                      cand, slots, tpc, out);
    } else {
        int* idxo = (int*)(out + 3 * B_VOX);   // alias out row 3 (read-before-write)
        argmax_naive<<<B_VOX / 256, 256, 0, stream>>>(ir, ii, yr, yi, idxo);
        finish_k<<<B_VOX / 256, 256, 0, stream>>>(ir, ii, yr, yi,
                                                  inv, x1, x2, idxo, out);
    }
}

// Round 9
// 296.074 us; speedup vs baseline: 1.6872x; 1.0322x over previous
//
#include <hip/hip_runtime.h>
#include <hip/hip_bf16.h>
#include <stdint.h>

#define M_TIME 64
#define N_DICT 20000
#define B_VOX  8192

#define NTILES 313    // ceil(20000/64); last tile padded with zeros

typedef short v8s __attribute__((ext_vector_type(8)));   // 8 bf16 (bit pattern)
typedef float v4f __attribute__((ext_vector_type(4)));
typedef __attribute__((address_space(3))) unsigned int  lds_u32;
typedef const __attribute__((address_space(1))) unsigned int glb_u32;

__device__ __forceinline__ unsigned short bf16h(float x) {   // RNE fp32->bf16
    unsigned int u = __float_as_uint(x);
    return (unsigned short)((u + 0x7fffu + ((u >> 16) & 1u)) >> 16);
}
__device__ __forceinline__ float bf16f(unsigned short h) {
    return __uint_as_float(((unsigned int)h) << 16);
}
__device__ __forceinline__ unsigned long long u64max(unsigned long long a, unsigned long long b) { return a > b ? a : b; }
__device__ __forceinline__ unsigned umin32(unsigned a, unsigned b) { return a < b ? a : b; }
__device__ __forceinline__ unsigned umax32(unsigned a, unsigned b) { return a > b ? a : b; }

// ---------------------------------------------------------------------------
// Prepass: split y into bf16 hi/lo ONCE, packed in A-FRAGMENT order:
// tile T has 32 fragment-rows fr = (t*2 + h)*4 + quad (t = yrh,yrl,yih,yil;
// h = K-half; quad = lane>>4); row = 64 n x 8 bf16 (k = h*32 + quad*8 + j).
// In-kernel fragment load = ONE ds_read_b128, zero repack VALU (round 8's
// ushort4->v8s assembly was ~500 VALU insts/tile/wave = 47% VALUBusy).
// ---------------------------------------------------------------------------
__global__ __launch_bounds__(256) void split_y(
    const float* __restrict__ yr, const float* __restrict__ yi,
    ushort4* __restrict__ yp)
{
    const int u = blockIdx.x * 256 + threadIdx.x;   // [arr][T][kq][n_l]
    const int n_l = u & 63;
    const int kq  = (u >> 6) & 15;      // k-quad: k = kq*4 + c
    const int T   = (u >> 10) % NTILES;
    const int arr = u / (NTILES * 1024);
    if (arr > 1) return;
    const float* P = arr ? yi : yr;
    const int n_g = T * 64 + n_l;
    float v0 = 0.f, v1 = 0.f, v2 = 0.f, v3 = 0.f;
    if (n_g < N_DICT) {
        v0 = P[(kq * 4 + 0) * N_DICT + n_g];
        v1 = P[(kq * 4 + 1) * N_DICT + n_g];
        v2 = P[(kq * 4 + 2) * N_DICT + n_g];
        v3 = P[(kq * 4 + 3) * N_DICT + n_g];
    }
    ushort4 H, L;
    H.x = bf16h(v0); L.x = bf16h(v0 - bf16f(H.x));
    H.y = bf16h(v1); L.y = bf16h(v1 - bf16f(H.y));
    H.z = bf16h(v2); L.z = bf16h(v2 - bf16f(H.z));
    H.w = bf16h(v3); L.w = bf16h(v3 - bf16f(H.w));
    // fragment-row decomposition of kq: h = kq>>3, quad = (kq>>1)&3, half = kq&1
    const int h    = kq >> 3;
    const int quad = (kq >> 1) & 3;
    const int half = kq & 1;
#pragma unroll
    for (int hl = 0; hl < 2; ++hl) {                 // 0 = hi, 1 = lo
        const int t  = arr * 2 + hl;
        const int fr = (t * 2 + h) * 4 + quad;
        yp[(((size_t)T * 32 + fr) * 64 + n_l) * 2 + half] = hl ? L : H;
    }
}

// ---------------------------------------------------------------------------
// Phase A: bf16-split MFMA GEMM + per-chunk top-2 (u32 packed comparator).
// LDS ping-pong (2 x 32 KB): DMA for tile T+1 issued right after the barrier,
// so the barrier's vmcnt(0) drain at T+1 waits on a load that had a full
// tile's compute to finish -> one cheap barrier per tile.
// Fragments load as single ds_read_b128 (pre-packed by split_y).
// ---------------------------------------------------------------------------
__global__ __launch_bounds__(256, 2) void gemm_pre(
    const float* __restrict__ ir, const float* __restrict__ ii,
    const ushort4* __restrict__ yp,
    unsigned* __restrict__ cand, int tpc, int slots)
{
    __shared__ float4 ys4[2][2048];         // 2 x 32 KB ping-pong
    __shared__ unsigned xm[2][2][16][2];    // [wb][bt][col][a1,a2]

    const int tid  = threadIdx.x;
    const int wave = tid >> 6, lane = tid & 63;
    const int quad = lane >> 4, col = lane & 15;
    const int wb   = wave >> 1, wn = wave & 1;
    const int vox_w = blockIdx.x * 64 + wb * 32;
    const int chunk = blockIdx.y;
    const int T0 = chunk * tpc;
    const int T1 = (T0 + tpc < NTILES) ? T0 + tpc : NTILES;

    // ---- prologue: DMA tile T0 into buffer 0 ----
    {
        const float4* src = (const float4*)(yp + (size_t)T0 * 4096);
#pragma unroll
        for (int p = 0; p < 8; ++p) {
            const int base = p * 256 + wave * 64;            // wave-uniform
            __builtin_amdgcn_global_load_lds(
                (glb_u32*)(src + base + lane),
                (lds_u32*)(&ys4[0][base]), 16, 0, 0);
        }
    }

    // ---- persistent input B-frags: [arr][bt][h] hi/lo (once per block) ----
    v8s fh[2][2][2], fl[2][2][2];
#pragma unroll
    for (int arr = 0; arr < 2; ++arr) {
        const float* P = arr ? ii : ir;
#pragma unroll
        for (int bt = 0; bt < 2; ++bt) {
            const int b = vox_w + bt * 16 + col;
#pragma unroll
            for (int h = 0; h < 2; ++h) {
                v8s H, L;
#pragma unroll
                for (int j = 0; j < 8; ++j) {
                    const int k = h * 32 + quad * 8 + j;
                    float x = P[k * B_VOX + b];
                    unsigned short hb = bf16h(x);
                    H[j] = (short)hb;
                    L[j] = (short)bf16h(x - bf16f(hb));
                }
                fh[arr][bt][h] = H; fl[arr][bt][h] = L;
            }
        }
    }

    unsigned t2a[2] = {0u, 0u}, t2b[2] = {0u, 0u};

    for (int T = T0; T < T1; ++T) {
        const int par = (T - T0) & 1;
        __syncthreads();   // drains DMA(T) into buf[par]; all waves done reading buf[1-par]
        if (T + 1 < T1) {  // overlap: DMA(T+1) into the buffer just freed
            const float4* src = (const float4*)(yp + (size_t)(T + 1) * 4096);
#pragma unroll
            for (int p = 0; p < 8; ++p) {
                const int base = p * 256 + wave * 64;
                __builtin_amdgcn_global_load_lds(
                    (glb_u32*)(src + base + lane),
                    (lds_u32*)(&ys4[par ^ 1][base]), 16, 0, 0);
            }
        }
        const v8s* yv = (const v8s*)ys4[par];

        v4f acc[2][2][4];                       // [bt][nt][rr,ri,s1,s2]
#pragma unroll
        for (int bt = 0; bt < 2; ++bt)
#pragma unroll
            for (int nt = 0; nt < 2; ++nt)
#pragma unroll
                for (int d = 0; d < 4; ++d) acc[bt][nt][d] = (v4f){0.f, 0.f, 0.f, 0.f};

#pragma unroll
        for (int h = 0; h < 2; ++h) {
#pragma unroll
            for (int nt = 0; nt < 2; ++nt) {
                const int nrow = (wn * 2 + nt) * 16 + col;
                v8s yf[4];                      // yrh, yrl, yih, yil
#pragma unroll
                for (int t = 0; t < 4; ++t)
                    yf[t] = yv[((t * 2 + h) * 4 + quad) * 64 + nrow];  // 1 ds_read_b128
#pragma unroll
                for (int bt = 0; bt < 2; ++bt) {
#define MF(A, B, C) C = __builtin_amdgcn_mfma_f32_16x16x32_bf16(A, B, C, 0, 0, 0)
                    MF(yf[0], fh[0][bt][h], acc[bt][nt][0]);   // rr: yrh*irh
                    MF(yf[0], fl[0][bt][h], acc[bt][nt][0]);   //     yrh*irl
                    MF(yf[1], fh[0][bt][h], acc[bt][nt][0]);   //     yrl*irh
                    MF(yf[2], fh[0][bt][h], acc[bt][nt][1]);   // ri
                    MF(yf[2], fl[0][bt][h], acc[bt][nt][1]);
                    MF(yf[3], fh[0][bt][h], acc[bt][nt][1]);
                    MF(yf[0], fh[1][bt][h], acc[bt][nt][2]);   // s1
                    MF(yf[0], fl[1][bt][h], acc[bt][nt][2]);
                    MF(yf[1], fh[1][bt][h], acc[bt][nt][2]);
                    MF(yf[2], fh[1][bt][h], acc[bt][nt][3]);   // s2
                    MF(yf[2], fl[1][bt][h], acc[bt][nt][3]);
                    MF(yf[3], fh[1][bt][h], acc[bt][nt][3]);
#undef MF
                }
            }
        }

        // ---- sim + top-2, u32 min/max network ----
        const int tl = T - T0;
#pragma unroll
        for (int nt = 0; nt < 2; ++nt) {
            const int inv_base = 0x1FFF - (tl * 64 + (wn * 2 + nt) * 16 + quad * 4);
#pragma unroll
            for (int bt = 0; bt < 2; ++bt) {
                v4f RR = acc[bt][nt][0], RI = acc[bt][nt][1];
                v4f S1 = acc[bt][nt][2], S2 = acc[bt][nt][3];
#pragma unroll
                for (int r = 0; r < 4; ++r) {
                    float s = fmaf(RR[r], RR[r], fmaf(RI[r], RI[r],
                              fmaf(S1[r], S1[r], S2[r] * S2[r])));
                    unsigned pb = (__float_as_uint(s) & 0xFFFFE000u)
                                | (unsigned)(inv_base - r);
                    unsigned lo = umin32(pb, t2a[bt]);
                    t2a[bt] = umax32(pb, t2a[bt]);
                    t2b[bt] = umax32(t2b[bt], lo);
                }
            }
        }
    }

    // ---- cross-lane top-2 merge over quads (lanes c, c+16, c+32, c+48) ----
    unsigned fa1[2], fa2[2];
#pragma unroll
    for (int bt = 0; bt < 2; ++bt) {
        unsigned a1 = t2a[bt], a2 = t2b[bt];
#pragma unroll
        for (int d = 16; d <= 32; d <<= 1) {
            unsigned b1 = (unsigned)__shfl_xor((int)a1, d, 64);
            unsigned b2 = (unsigned)__shfl_xor((int)a2, d, 64);
            unsigned mn = umin32(a1, b1);
            a1 = umax32(a1, b1);
            a2 = umax32(mn, umax32(a2, b2));
        }
        fa1[bt] = a1; fa2[bt] = a2;
    }
    // ---- cross-wave (wn) merge: wn==1 publishes, wn==0 writes ----
    __syncthreads();
    if (wn == 1 && lane < 16) {
#pragma unroll
        for (int bt = 0; bt < 2; ++bt) { xm[wb][bt][lane][0] = fa1[bt]; xm[wb][bt][lane][1] = fa2[bt]; }
    }
    __syncthreads();
    if (wn == 0 && lane < 16) {
#pragma unroll
        for (int bt = 0; bt < 2; ++bt) {
            unsigned b1 = xm[wb][bt][lane][0];
            unsigned b2 = xm[wb][bt][lane][1];
            unsigned m1 = umax32(fa1[bt], b1);
            unsigned m2 = umax32(umin32(fa1[bt], b1), umax32(fa2[bt], b2));
            const size_t vox = vox_w + bt * 16 + lane;
            cand[vox * slots + chunk * 2 + 0] = m1;
            cand[vox * slots + chunk * 2 + 1] = m2;
        }
    }
}

// ---------------------------------------------------------------------------
// Phase B (fused): exact fp32 rescore of candidates within 2% of approx max,
// winner lane computes scales and writes the 4 output rows directly.
// One wave per voxel.
// ---------------------------------------------------------------------------
__global__ __launch_bounds__(256) void rescore_finish(
    const float* __restrict__ ir, const float* __restrict__ ii,
    const float* __restrict__ yr, const float* __restrict__ yi,
    const float* __restrict__ inv, const float* __restrict__ x1,
    const float* __restrict__ x2,
    const unsigned* __restrict__ cand, int slots, int tpc,
    float* __restrict__ out)
{
    const int tid  = threadIdx.x;
    const int vox  = blockIdx.x * 4 + (tid >> 6);
    const int slot = tid & 63;

    unsigned p = (slot < slots) ? cand[(size_t)vox * slots + slot] : 0u;
    float sa = __uint_as_float(p & 0xFFFFE000u);
    const int chunkc = slot >> 1;
    const int nn = chunkc * tpc * 64 + (0x1FFF - (int)(p & 0x1FFFu));

    float amax = sa;
#pragma unroll
    for (int d = 1; d <= 32; d <<= 1) amax = fmaxf(amax, __shfl_xor(amax, d, 64));

    unsigned long long q = 0ull;
    float rr = 0.f, ri = 0.f, s1 = 0.f, s2 = 0.f;
    const bool active = (slot < slots) && (nn >= 0) && (nn < N_DICT)
                     && (sa >= 0.98f * amax);
    if (active) {
        for (int m = 0; m < M_TIME; ++m) {
            float a  = yr[(size_t)m * N_DICT + nn];
            float c  = yi[(size_t)m * N_DICT + nn];
            float vr = ir[m * B_VOX + vox];
            float vi = ii[m * B_VOX + vox];
            rr = fmaf(vr, a, rr); ri = fmaf(vr, c, ri);
            s1 = fmaf(vi, a, s1); s2 = fmaf(vi, c, s2);
        }
        float s = fmaf(rr, rr, fmaf(ri, ri, fmaf(s1, s1, s2 * s2)));
        q = (((unsigned long long)__float_as_uint(s)) << 32)
          | (unsigned long long)(0xFFFFFFFFu - (unsigned)nn);  // ties -> smaller n
    }
    unsigned long long qm = q;
#pragma unroll
    for (int d = 1; d <= 32; d <<= 1) qm = u64max(qm, __shfl_xor(qm, d, 64));

    if (active && q == qm && qm != 0ull) {       // exactly one lane (n in key)
        float ss = inv[nn];
        out[0 * B_VOX + vox] = (rr + s2) * ss;   // sum(yr*ir + yi*ii) * inv
        out[1 * B_VOX + vox] = (s1 - ri) * ss;   // sum(yr*ii - yi*ir) * inv
        out[2 * B_VOX + vox] = x1[nn];
        out[3 * B_VOX + vox] = x2[nn];
    }
}

// ---------------------------------------------------------------------------
// Last-resort fallbacks (tiny ws): fp32 brute-force argmax + finish.
// ---------------------------------------------------------------------------
__global__ __launch_bounds__(256, 3) void argmax_naive(
    const float* __restrict__ ir, const float* __restrict__ ii,
    const float* __restrict__ yr, const float* __restrict__ yi,
    int* __restrict__ idxout)
{
    int b = blockIdx.x * 256 + threadIdx.x;
    float bs = -1.0f; int bn = 0;
    for (int n = 0; n < N_DICT; ++n) {
        float a_rr = 0.f, a_ri = 0.f, a_s1 = 0.f, a_s2 = 0.f;
        for (int m = 0; m < M_TIME; ++m) {
            float a = yr[m * N_DICT + n], c = yi[m * N_DICT + n];
            float vr = ir[m * B_VOX + b], vi = ii[m * B_VOX + b];
            a_rr = fmaf(vr, a, a_rr); a_ri = fmaf(vr, c, a_ri);
            a_s1 = fmaf(vi, a, a_s1); a_s2 = fmaf(vi, c, a_s2);
        }
        float sim = fmaf(a_rr, a_rr, fmaf(a_ri, a_ri, fmaf(a_s1, a_s1, a_s2 * a_s2)));
        if (sim > bs) { bs = sim; bn = n; }
    }
    idxout[b] = bn;
}

__global__ void finish_k(const float* __restrict__ ir, const float* __restrict__ ii,
                         const float* __restrict__ yr, const float* __restrict__ yi,
                         const float* __restrict__ inv, const float* __restrict__ x1,
                         const float* __restrict__ x2,
                         const int* __restrict__ idxin, float* __restrict__ out)
{
    int b = blockIdx.x * blockDim.x + threadIdx.x;
    int idx = idxin[b];
    float ar = 0.f, ai = 0.f;
    for (int m = 0; m < M_TIME; ++m) {
        float a  = yr[(size_t)m * N_DICT + idx];
        float c  = yi[(size_t)m * N_DICT + idx];
        float vr = ir[m * B_VOX + b];
        float vi = ii[m * B_VOX + b];
        ar = fmaf(a, vr, ar); ar = fmaf(c, vi, ar);
        ai = fmaf(a, vi, ai); ai = fmaf(-c, vr, ai);
    }
    float s = inv[idx];
    out[0 * B_VOX + b] = ar * s;
    out[1 * B_VOX + b] = ai * s;
    out[2 * B_VOX + b] = x1[idx];
    out[3 * B_VOX + b] = x2[idx];
}

extern "C" void kernel_launch(void* const* d_in, const int* in_sizes, int n_in,
                              void* d_out, int out_size, void* d_ws, size_t ws_size,
                              hipStream_t stream) {
    const float* ir  = (const float*)d_in[0];
    const float* ii  = (const float*)d_in[1];
    const float* yr  = (const float*)d_in[2];
    const float* yi  = (const float*)d_in[3];
    const float* inv = (const float*)d_in[4];
    const float* x1  = (const float*)d_in[5];
    const float* x2  = (const float*)d_in[6];
    float* out = (float*)d_out;

    const size_t yp_bytes = (size_t)NTILES * 4096 * sizeof(ushort4);   // 10.26 MB

    // pick largest chunk count whose cand buffer fits alongside yp
    int CH = 0;
    for (int c = 16; c >= 4; c >>= 1) {
        size_t cand_bytes = (size_t)B_VOX * (2 * c) * sizeof(unsigned);
        if (ws_size >= cand_bytes + yp_bytes) { CH = c; break; }
    }

    if (CH > 0) {
        const int slots = 2 * CH;
        const int tpc   = (NTILES + CH - 1) / CH;
        unsigned* cand = (unsigned*)d_ws;
        ushort4* yp = (ushort4*)((char*)d_ws + (size_t)B_VOX * slots * sizeof(unsigned));

        const int units = 2 * NTILES * 1024;
        split_y<<<(units + 255) / 256, 256, 0, stream>>>(yr, yi, yp);
        gemm_pre<<<dim3(B_VOX / 64, CH), 256, 0, stream>>>(ir, ii, yp, cand, tpc, slots);
        rescore_finish<<<B_VOX / 4, 256, 0, stream>>>(ir, ii, yr, yi, inv, x1, x2,
                                                      cand, slots, tpc, out);
    } else {
        int* idxo = (int*)(out + 3 * B_VOX);   // alias out row 3 (read-before-write)
        argmax_naive<<<B_VOX / 256, 256, 0, stream>>>(ir, ii, yr, yi, idxo);
        finish_k<<<B_VOX / 256, 256, 0, stream>>>(ir, ii, yr, yi,
                                                  inv, x1, x2, idxo, out);
    }
}

// Round 10
// 241.749 us; speedup vs baseline: 2.0663x; 1.2247x over previous
//
#include <hip/hip_runtime.h>
#include <hip/hip_bf16.h>
#include <stdint.h>

#define M_TIME 64
#define N_DICT 20000
#define B_VOX  8192

#define NTILES 313    // ceil(20000/64); last tile padded with zeros

typedef _Float16 v8h __attribute__((ext_vector_type(8)));   // 8 f16 (4 VGPRs)
typedef _Float16 v4h __attribute__((ext_vector_type(4)));   // 8 B store unit
typedef float    v4f __attribute__((ext_vector_type(4)));
typedef __attribute__((address_space(3))) unsigned int  lds_u32;
typedef const __attribute__((address_space(1))) unsigned int glb_u32;

__device__ __forceinline__ unsigned long long u64max(unsigned long long a, unsigned long long b) { return a > b ? a : b; }
__device__ __forceinline__ unsigned umin32(unsigned a, unsigned b) { return a < b ? a : b; }
__device__ __forceinline__ unsigned umax32(unsigned a, unsigned b) { return a > b ? a : b; }

// ---------------------------------------------------------------------------
// Prepass: convert y to single f16 ONCE, packed in A-fragment order.
// Tile T = 16 fragment-rows fr = (t*2 + h)*4 + quad (t = {yr,yi}, h = K-half,
// quad = lane>>4); row = 64 n x 8 f16 (k = h*32 + quad*8 + j). 16 KB/tile.
// f16 (11-bit mantissa) y + exact hi/lo-split input gives sim rel-err ~6e-4,
// 30x inside the 2% exact-rescue margin -- and only 2 MFMA terms (was 3).
// ---------------------------------------------------------------------------
__global__ __launch_bounds__(256) void split_y(
    const float* __restrict__ yr, const float* __restrict__ yi,
    v4h* __restrict__ yp)
{
    const int u = blockIdx.x * 256 + threadIdx.x;   // [arr][T][kq][n_l]
    const int n_l = u & 63;
    const int kq  = (u >> 6) & 15;      // k-quad: k = kq*4 + c
    const int T   = (u >> 10) % NTILES;
    const int arr = u / (NTILES * 1024);
    if (arr > 1) return;
    const float* P = arr ? yi : yr;
    const int n_g = T * 64 + n_l;
    float v0 = 0.f, v1 = 0.f, v2 = 0.f, v3 = 0.f;
    if (n_g < N_DICT) {
        v0 = P[(kq * 4 + 0) * N_DICT + n_g];
        v1 = P[(kq * 4 + 1) * N_DICT + n_g];
        v2 = P[(kq * 4 + 2) * N_DICT + n_g];
        v3 = P[(kq * 4 + 3) * N_DICT + n_g];
    }
    v4h V;
    V[0] = (_Float16)v0; V[1] = (_Float16)v1;
    V[2] = (_Float16)v2; V[3] = (_Float16)v3;
    const int h    = kq >> 3;
    const int quad = (kq >> 1) & 3;
    const int half = kq & 1;
    const int fr   = (arr * 2 + h) * 4 + quad;
    yp[((size_t)T * 16 + fr) * 128 + n_l * 2 + half] = V;
}

// ---------------------------------------------------------------------------
// Phase A: f16 2-term MFMA GEMM + per-chunk top-2 (u32 packed comparator).
// d = y_f16 * (in_hi + in_lo): 8 MFMA per (h,nt,bt) vs 12 for bf16 3-term.
// Zero-C trick kills the acc-init movs; 16 KB ping-pong LDS; DMA staging.
// launch_bounds(256,3): target 3 waves/SIMD so sim-epilogue VALU overlaps
// other waves' MFMA (round 9 ran the pipes serially at 2 waves/SIMD).
// ---------------------------------------------------------------------------
__global__ __launch_bounds__(256, 3) void gemm_pre(
    const float* __restrict__ ir, const float* __restrict__ ii,
    const v4h* __restrict__ yp,
    unsigned* __restrict__ cand, int tpc, int slots)
{
    __shared__ float4 ys4[2][1024];         // 2 x 16 KB ping-pong
    __shared__ unsigned xm[2][2][16][2];    // [wb][bt][col][a1,a2]

    const int tid  = threadIdx.x;
    const int wave = tid >> 6, lane = tid & 63;
    const int quad = lane >> 4, col = lane & 15;
    const int wb   = wave >> 1, wn = wave & 1;
    const int vox_w = blockIdx.x * 64 + wb * 32;
    const int chunk = blockIdx.y;
    const int T0 = chunk * tpc;
    const int T1 = (T0 + tpc < NTILES) ? T0 + tpc : NTILES;

    // ---- prologue: DMA tile T0 into buffer 0 (4 x 64 lanes x 16 B / wave) ----
    {
        const float4* src = (const float4*)((const char*)yp + (size_t)T0 * 16384);
#pragma unroll
        for (int p = 0; p < 4; ++p) {
            const int base = p * 256 + wave * 64;            // wave-uniform
            __builtin_amdgcn_global_load_lds(
                (glb_u32*)(src + base + lane),
                (lds_u32*)(&ys4[0][base]), 16, 0, 0);
        }
    }

    // ---- persistent input B-frags: [arr][bt][h] f16 hi/lo (exact split) ----
    v8h fh[2][2][2], fl[2][2][2];
#pragma unroll
    for (int arr = 0; arr < 2; ++arr) {
        const float* P = arr ? ii : ir;
#pragma unroll
        for (int bt = 0; bt < 2; ++bt) {
            const int b = vox_w + bt * 16 + col;
#pragma unroll
            for (int h = 0; h < 2; ++h) {
                v8h H, L;
#pragma unroll
                for (int j = 0; j < 8; ++j) {
                    const int k = h * 32 + quad * 8 + j;
                    float x = P[k * B_VOX + b];
                    _Float16 hh = (_Float16)x;
                    H[j] = hh;
                    L[j] = (_Float16)(x - (float)hh);
                }
                fh[arr][bt][h] = H; fl[arr][bt][h] = L;
            }
        }
    }

    const v4f zc = {0.f, 0.f, 0.f, 0.f};
    unsigned t2a[2] = {0u, 0u}, t2b[2] = {0u, 0u};

    for (int T = T0; T < T1; ++T) {
        const int par = (T - T0) & 1;
        __syncthreads();   // drains DMA(T) into buf[par]; buf[par^1] now free
        if (T + 1 < T1) {  // overlap: DMA(T+1) into the freed buffer
            const float4* src = (const float4*)((const char*)yp + (size_t)(T + 1) * 16384);
#pragma unroll
            for (int p = 0; p < 4; ++p) {
                const int base = p * 256 + wave * 64;
                __builtin_amdgcn_global_load_lds(
                    (glb_u32*)(src + base + lane),
                    (lds_u32*)(&ys4[par ^ 1][base]), 16, 0, 0);
            }
        }
        const v8h* yv = (const v8h*)ys4[par];

        v4f acc[2][2][4];                       // [bt][nt][rr,ri,s1,s2]
#pragma unroll
        for (int h = 0; h < 2; ++h) {
#pragma unroll
            for (int nt = 0; nt < 2; ++nt) {
                const int nrow = (wn * 2 + nt) * 16 + col;
                const v8h yfr = yv[((0 * 2 + h) * 4 + quad) * 64 + nrow];  // yr frag
                const v8h yfi = yv[((1 * 2 + h) * 4 + quad) * 64 + nrow];  // yi frag
#pragma unroll
                for (int bt = 0; bt < 2; ++bt) {
#define MF(A, B, C) __builtin_amdgcn_mfma_f32_16x16x32_f16(A, B, C, 0, 0, 0)
                    if (h == 0) {               // first k-half: C = zero (no init movs)
                        acc[bt][nt][0] = MF(yfr, fh[0][bt][0], zc);
                        acc[bt][nt][1] = MF(yfi, fh[0][bt][0], zc);
                        acc[bt][nt][2] = MF(yfr, fh[1][bt][0], zc);
                        acc[bt][nt][3] = MF(yfi, fh[1][bt][0], zc);
                        acc[bt][nt][0] = MF(yfr, fl[0][bt][0], acc[bt][nt][0]);
                        acc[bt][nt][1] = MF(yfi, fl[0][bt][0], acc[bt][nt][1]);
                        acc[bt][nt][2] = MF(yfr, fl[1][bt][0], acc[bt][nt][2]);
                        acc[bt][nt][3] = MF(yfi, fl[1][bt][0], acc[bt][nt][3]);
                    } else {
                        acc[bt][nt][0] = MF(yfr, fh[0][bt][1], acc[bt][nt][0]);
                        acc[bt][nt][1] = MF(yfi, fh[0][bt][1], acc[bt][nt][1]);
                        acc[bt][nt][2] = MF(yfr, fh[1][bt][1], acc[bt][nt][2]);
                        acc[bt][nt][3] = MF(yfi, fh[1][bt][1], acc[bt][nt][3]);
                        acc[bt][nt][0] = MF(yfr, fl[0][bt][1], acc[bt][nt][0]);
                        acc[bt][nt][1] = MF(yfi, fl[0][bt][1], acc[bt][nt][1]);
                        acc[bt][nt][2] = MF(yfr, fl[1][bt][1], acc[bt][nt][2]);
                        acc[bt][nt][3] = MF(yfi, fl[1][bt][1], acc[bt][nt][3]);
                    }
#undef MF
                }
            }
        }

        // ---- sim + top-2, u32 min/max network ----
        const int tl = T - T0;
#pragma unroll
        for (int nt = 0; nt < 2; ++nt) {
            const int inv_base = 0x1FFF - (tl * 64 + (wn * 2 + nt) * 16 + quad * 4);
#pragma unroll
            for (int bt = 0; bt < 2; ++bt) {
                v4f RR = acc[bt][nt][0], RI = acc[bt][nt][1];
                v4f S1 = acc[bt][nt][2], S2 = acc[bt][nt][3];
#pragma unroll
                for (int r = 0; r < 4; ++r) {
                    float s = fmaf(RR[r], RR[r], fmaf(RI[r], RI[r],
                              fmaf(S1[r], S1[r], S2[r] * S2[r])));
                    unsigned pb = (__float_as_uint(s) & 0xFFFFE000u)
                                | (unsigned)(inv_base - r);
                    unsigned lo = umin32(pb, t2a[bt]);
                    t2a[bt] = umax32(pb, t2a[bt]);
                    t2b[bt] = umax32(t2b[bt], lo);
                }
            }
        }
    }

    // ---- cross-lane top-2 merge over quads (lanes c, c+16, c+32, c+48) ----
    unsigned fa1[2], fa2[2];
#pragma unroll
    for (int bt = 0; bt < 2; ++bt) {
        unsigned a1 = t2a[bt], a2 = t2b[bt];
#pragma unroll
        for (int d = 16; d <= 32; d <<= 1) {
            unsigned b1 = (unsigned)__shfl_xor((int)a1, d, 64);
            unsigned b2 = (unsigned)__shfl_xor((int)a2, d, 64);
            unsigned mn = umin32(a1, b1);
            a1 = umax32(a1, b1);
            a2 = umax32(mn, umax32(a2, b2));
        }
        fa1[bt] = a1; fa2[bt] = a2;
    }
    // ---- cross-wave (wn) merge: wn==1 publishes, wn==0 writes ----
    __syncthreads();
    if (wn == 1 && lane < 16) {
#pragma unroll
        for (int bt = 0; bt < 2; ++bt) { xm[wb][bt][lane][0] = fa1[bt]; xm[wb][bt][lane][1] = fa2[bt]; }
    }
    __syncthreads();
    if (wn == 0 && lane < 16) {
#pragma unroll
        for (int bt = 0; bt < 2; ++bt) {
            unsigned b1 = xm[wb][bt][lane][0];
            unsigned b2 = xm[wb][bt][lane][1];
            unsigned m1 = umax32(fa1[bt], b1);
            unsigned m2 = umax32(umin32(fa1[bt], b1), umax32(fa2[bt], b2));
            const size_t vox = vox_w + bt * 16 + lane;
            cand[vox * slots + chunk * 2 + 0] = m1;
            cand[vox * slots + chunk * 2 + 1] = m2;
        }
    }
}

// ---------------------------------------------------------------------------
// Phase B (fused): exact fp32 rescore of candidates within 2% of approx max,
// winner lane computes scales and writes the 4 output rows directly.
// One wave per voxel.
// ---------------------------------------------------------------------------
__global__ __launch_bounds__(256) void rescore_finish(
    const float* __restrict__ ir, const float* __restrict__ ii,
    const float* __restrict__ yr, const float* __restrict__ yi,
    const float* __restrict__ inv, const float* __restrict__ x1,
    const float* __restrict__ x2,
    const unsigned* __restrict__ cand, int slots, int tpc,
    float* __restrict__ out)
{
    const int tid  = threadIdx.x;
    const int vox  = blockIdx.x * 4 + (tid >> 6);
    const int slot = tid & 63;

    unsigned p = (slot < slots) ? cand[(size_t)vox * slots + slot] : 0u;
    float sa = __uint_as_float(p & 0xFFFFE000u);
    const int chunkc = slot >> 1;
    const int nn = chunkc * tpc * 64 + (0x1FFF - (int)(p & 0x1FFFu));

    float amax = sa;
#pragma unroll
    for (int d = 1; d <= 32; d <<= 1) amax = fmaxf(amax, __shfl_xor(amax, d, 64));

    unsigned long long q = 0ull;
    float rr = 0.f, ri = 0.f, s1 = 0.f, s2 = 0.f;
    const bool active = (slot < slots) && (nn >= 0) && (nn < N_DICT)
                     && (sa >= 0.98f * amax);
    if (active) {
        for (int m = 0; m < M_TIME; ++m) {
            float a  = yr[(size_t)m * N_DICT + nn];
            float c  = yi[(size_t)m * N_DICT + nn];
            float vr = ir[m * B_VOX + vox];
            float vi = ii[m * B_VOX + vox];
            rr = fmaf(vr, a, rr); ri = fmaf(vr, c, ri);
            s1 = fmaf(vi, a, s1); s2 = fmaf(vi, c, s2);
        }
        float s = fmaf(rr, rr, fmaf(ri, ri, fmaf(s1, s1, s2 * s2)));
        q = (((unsigned long long)__float_as_uint(s)) << 32)
          | (unsigned long long)(0xFFFFFFFFu - (unsigned)nn);  // ties -> smaller n
    }
    unsigned long long qm = q;
#pragma unroll
    for (int d = 1; d <= 32; d <<= 1) qm = u64max(qm, __shfl_xor(qm, d, 64));

    if (active && q == qm && qm != 0ull) {       // exactly one lane (n in key)
        float ss = inv[nn];
        out[0 * B_VOX + vox] = (rr + s2) * ss;   // sum(yr*ir + yi*ii) * inv
        out[1 * B_VOX + vox] = (s1 - ri) * ss;   // sum(yr*ii - yi*ir) * inv
        out[2 * B_VOX + vox] = x1[nn];
        out[3 * B_VOX + vox] = x2[nn];
    }
}

// ---------------------------------------------------------------------------
// Last-resort fallbacks (tiny ws): fp32 brute-force argmax + finish.
// ---------------------------------------------------------------------------
__global__ __launch_bounds__(256, 3) void argmax_naive(
    const float* __restrict__ ir, const float* __restrict__ ii,
    const float* __restrict__ yr, const float* __restrict__ yi,
    int* __restrict__ idxout)
{
    int b = blockIdx.x * 256 + threadIdx.x;
    float bs = -1.0f; int bn = 0;
    for (int n = 0; n < N_DICT; ++n) {
        float a_rr = 0.f, a_ri = 0.f, a_s1 = 0.f, a_s2 = 0.f;
        for (int m = 0; m < M_TIME; ++m) {
            float a = yr[m * N_DICT + n], c = yi[m * N_DICT + n];
            float vr = ir[m * B_VOX + b], vi = ii[m * B_VOX + b];
            a_rr = fmaf(vr, a, a_rr); a_ri = fmaf(vr, c, a_ri);
            a_s1 = fmaf(vi, a, a_s1); a_s2 = fmaf(vi, c, a_s2);
        }
        float sim = fmaf(a_rr, a_rr, fmaf(a_ri, a_ri, fmaf(a_s1, a_s1, a_s2 * a_s2)));
        if (sim > bs) { bs = sim; bn = n; }
    }
    idxout[b] = bn;
}

__global__ void finish_k(const float* __restrict__ ir, const float* __restrict__ ii,
                         const float* __restrict__ yr, const float* __restrict__ yi,
                         const float* __restrict__ inv, const float* __restrict__ x1,
                         const float* __restrict__ x2,
                         const int* __restrict__ idxin, float* __restrict__ out)
{
    int b = blockIdx.x * blockDim.x + threadIdx.x;
    int idx = idxin[b];
    float ar = 0.f, ai = 0.f;
    for (int m = 0; m < M_TIME; ++m) {
        float a  = yr[(size_t)m * N_DICT + idx];
        float c  = yi[(size_t)m * N_DICT + idx];
        float vr = ir[m * B_VOX + b];
        float vi = ii[m * B_VOX + b];
        ar = fmaf(a, vr, ar); ar = fmaf(c, vi, ar);
        ai = fmaf(a, vi, ai); ai = fmaf(-c, vr, ai);
    }
    float s = inv[idx];
    out[0 * B_VOX + b] = ar * s;
    out[1 * B_VOX + b] = ai * s;
    out[2 * B_VOX + b] = x1[idx];
    out[3 * B_VOX + b] = x2[idx];
}

extern "C" void kernel_launch(void* const* d_in, const int* in_sizes, int n_in,
                              void* d_out, int out_size, void* d_ws, size_t ws_size,
                              hipStream_t stream) {
    const float* ir  = (const float*)d_in[0];
    const float* ii  = (const float*)d_in[1];
    const float* yr  = (const float*)d_in[2];
    const float* yi  = (const float*)d_in[3];
    const float* inv = (const float*)d_in[4];
    const float* x1  = (const float*)d_in[5];
    const float* x2  = (const float*)d_in[6];
    float* out = (float*)d_out;

    const size_t yp_bytes = (size_t)NTILES * 16384;    // 5.13 MB (f16 frag tiles)

    // pick largest chunk count whose cand buffer fits alongside yp
    int CH = 0;
    for (int c = 16; c >= 4; c >>= 1) {
        size_t cand_bytes = (size_t)B_VOX * (2 * c) * sizeof(unsigned);
        if (ws_size >= cand_bytes + yp_bytes) { CH = c; break; }
    }

    if (CH > 0) {
        const int slots = 2 * CH;
        const int tpc   = (NTILES + CH - 1) / CH;
        unsigned* cand = (unsigned*)d_ws;
        v4h* yp = (v4h*)((char*)d_ws + (size_t)B_VOX * slots * sizeof(unsigned));

        const int units = 2 * NTILES * 1024;
        split_y<<<(units + 255) / 256, 256, 0, stream>>>(yr, yi, yp);
        gemm_pre<<<dim3(B_VOX / 64, CH), 256, 0, stream>>>(ir, ii, yp, cand, tpc, slots);
        rescore_finish<<<B_VOX / 4, 256, 0, stream>>>(ir, ii, yr, yi, inv, x1, x2,
                                                      cand, slots, tpc, out);
    } else {
        int* idxo = (int*)(out + 3 * B_VOX);   // alias out row 3 (read-before-write)
        argmax_naive<<<B_VOX / 256, 256, 0, stream>>>(ir, ii, yr, yi, idxo);
        finish_k<<<B_VOX / 256, 256, 0, stream>>>(ir, ii, yr, yi,
                                                  inv, x1, x2, idxo, out);
    }
}